// Round 10
// baseline (262.255 us; speedup 1.0000x reference)
//
#include <hip/hip_runtime.h>
#include <cstdint>
#include <cstddef>

typedef unsigned short ushort_t;
typedef __attribute__((ext_vector_type(8))) short short8;
typedef __attribute__((ext_vector_type(4))) float float4v;
typedef __attribute__((ext_vector_type(4))) unsigned short ushort4v;

// ---------- bf16 helpers ----------
__device__ __forceinline__ float b2f(ushort_t u) {
    uint32_t x = ((uint32_t)u) << 16;
    float f;
    __builtin_memcpy(&f, &x, 4);
    return f;
}
__device__ __forceinline__ ushort_t f2b(float f) {  // RNE
    uint32_t x;
    __builtin_memcpy(&x, &f, 4);
    uint32_t r = (x + 0x7fffu + ((x >> 16) & 1u)) >> 16;
    return (ushort_t)r;
}
__device__ __forceinline__ ushort_t f2b_trunc(float f) {  // truncate (P-matrix only)
    uint32_t x;
    __builtin_memcpy(&x, &f, 4);
    return (ushort_t)(x >> 16);
}

// ---------- direct global->LDS (16B/lane; LDS dest = wave-uniform base + lane*16) ----------
typedef __attribute__((address_space(3))) void lds_void;
typedef __attribute__((address_space(1))) const void gbl_void;
__device__ __forceinline__ void gload16(const void* g, void* l) {
    __builtin_amdgcn_global_load_lds((gbl_void*)(uintptr_t)g, (lds_void*)(uintptr_t)l, 16, 0, 0);
}

// ---------- dtype detector ----------
__global__ void detect_dtype(const ushort_t* __restrict__ cosp, int* __restrict__ flag) {
    int tid = threadIdx.x;
    int bad = 0;
    for (int i = tid; i < 512; i += 64) {
        ushort_t u = cosp[i];
        int sign = u >> 15;
        int e = (u >> 7) & 0xFF;
        if (sign || e > 126) bad = 1;
    }
    int anybad = __any(bad);
    if (tid == 0) *flag = anybad ? 1 : 0;  // 1 => inputs are fp32
}

// ---------- merged preprocessing: W-transpose (z 0-3), cos/sin (z 4), X convert (z 5-12) ----------
__global__ __launch_bounds__(256) void prep_all(const void* __restrict__ x,
                                                ushort_t* __restrict__ xb,
                                                const void* __restrict__ c,
                                                const void* __restrict__ s,
                                                ushort_t* __restrict__ cb,
                                                ushort_t* __restrict__ sb,
                                                const void* __restrict__ w0,
                                                const void* __restrict__ w1,
                                                const void* __restrict__ w2,
                                                const void* __restrict__ w3,
                                                ushort_t* __restrict__ wt,
                                                const int* __restrict__ flag) {
    __shared__ ushort_t tile[32][33];
    int z = blockIdx.z;
    int f = *flag;
    if (z < 4) {
        const void* in = (z == 0) ? w0 : (z == 1) ? w1 : (z == 2) ? w2 : w3;
        ushort_t* o = wt + (size_t)z * 1024 * 1024;
        int bx = blockIdx.x * 32;
        int by = blockIdx.y * 32;
        int tx = threadIdx.x & 31;
        int ty = threadIdx.x >> 5;
        for (int r = ty; r < 32; r += 8) {
            size_t idx = (size_t)(by + r) * 1024 + bx + tx;
            tile[r][tx] = f ? f2b(((const float*)in)[idx]) : ((const ushort_t*)in)[idx];
        }
        __syncthreads();
        for (int r = ty; r < 32; r += 8)
            o[(size_t)(bx + r) * 1024 + by + tx] = tile[tx][r];
    } else if (z == 4) {
        int i = (blockIdx.y * 32 + blockIdx.x) * 256 + threadIdx.x;
        if (i < 131072) {
            if (f) {
                cb[i] = f2b(((const float*)c)[i]);
                sb[i] = f2b(((const float*)s)[i]);
            } else {
                cb[i] = ((const ushort_t*)c)[i];
                sb[i] = ((const ushort_t*)s)[i];
            }
        }
    } else {
        if (f == 0) return;
        int bid = (z - 5) * 1024 + blockIdx.y * 32 + blockIdx.x;
        int i = (bid * 256 + threadIdx.x) * 4;
        float4v v = *(const float4v*)((const float*)x + i);
        ushort4v o4;
#pragma unroll
        for (int j = 0; j < 4; ++j) o4[j] = f2b(v[j]);
        *(ushort4v*)(xb + i) = o4;
    }
}

template <int W>
__device__ __forceinline__ void vm_wait() {
    if constexpr (W == 8)      asm volatile("s_waitcnt vmcnt(8)" ::: "memory");
    else if constexpr (W == 6) asm volatile("s_waitcnt vmcnt(6)" ::: "memory");
    else if constexpr (W == 4) asm volatile("s_waitcnt vmcnt(4)" ::: "memory");
    else if constexpr (W == 0) asm volatile("s_waitcnt vmcnt(0)" ::: "memory");
    // W < 0: no wait
}
#define KBAR()                                       \
    do {                                             \
        asm volatile("" ::: "memory");               \
        __builtin_amdgcn_s_barrier();                \
        asm volatile("" ::: "memory");               \
    } while (0)

// ====================================================================
// fused QKV GEMM + RoPE + V-transpose — m201-style 8-phase 256x256.
// BK=64, 8 waves (2M x 4N, per-wave 128x64), LDS 128KB =
// 2buf x 2 K-halves x (A 256x32 | B 256x32), each half 16 KB.
// Phase = (kh, m-group): {ds_read 4-8 frags; stage 1 half (2 gload_lds);
// [vmcnt(8) at .2/.4 only]; barrier; lgkmcnt(0); setprio1; 16 MFMA;
// setprio0; barrier}. NO sched_barrier (m141: order-pinning kills perf).
// Stage schedule: phase .1/.2 stage kh1(j+1); .3/.4 stage kh0(j+2) --
// every staged half lands 4-6 phases before its first read; vmcnt(8)
// at .2/.4 forces exactly the needed (oldest) halves, never drains.
// Swizzle: 16B-slot ^= (row&3) on 64B rows; inverse-swizzled global src
// + linear gload_lds dest + swizzled ds_read (rule #21 involution).
// Grid 384 = 8 xcd x (4 m-pinned x 12 n); X slice 2MB/XCD in L2.
// Q pre-scaled by 0.125*log2(e) so attn softmax = exp2(raw).
// ====================================================================
__global__ __launch_bounds__(512, 2) void gemm_qkv(const ushort_t* __restrict__ X0,
                                                   const ushort_t* __restrict__ X1,
                                                   const ushort_t* __restrict__ Wt,
                                                   ushort_t* __restrict__ qk,
                                                   ushort_t* __restrict__ vt,
                                                   const ushort_t* __restrict__ cosb,
                                                   const ushort_t* __restrict__ sinb,
                                                   const int* __restrict__ flagp) {
    __shared__ ushort_t LDS[65536];  // 128 KB: slot(buf,kh,isB) = 16 KB each
    char* LDSc = (char*)LDS;

    int tid = threadIdx.x;
    int lane = tid & 63;
    int wave = tid >> 6;   // 0..7
    int wm = wave >> 2;    // 0..1  (M half: 128 rows)
    int wn = wave & 3;     // 0..3  (N quarter: 64 cols)
    int quad = lane >> 4;
    int l16 = lane & 15;

    // grid 384 = 8 xcd * (4 m_loc * 12 n)
    int id = blockIdx.x;
    int xcd = id & 7;
    int r = id >> 3;               // 0..47
    int m0 = (xcd * 4 + (r & 3)) * 256;
    int n0 = (r >> 2) * 256;

    const ushort_t* Xb = (*flagp) ? X1 : X0;

    // staging: per gload a wave writes 16 rows x 64B linear; lane l covers
    // row (l>>2), dest slot l&3; src k-slot pre-swizzled = (l&3)^((l>>2)&3).
    const ushort_t* aS = Xb + (size_t)(m0 + wave * 32 + (lane >> 2)) * 1024 +
                         (((lane & 3) ^ ((lane >> 2) & 3)) * 8);
    const ushort_t* bS = Wt + (size_t)(n0 + wave * 32 + (lane >> 2)) * 1024 +
                         (((lane & 3) ^ ((lane >> 2) & 3)) * 8);

    // frag read offsets within a 16KB half (rows x 64B, swizzled slots)
    int aoff = (wm * 128 + l16) * 64 + ((quad ^ (l16 & 3)) * 16);  // + i*1024
    int boff = (wn * 64 + l16) * 64 + ((quad ^ (l16 & 3)) * 16);   // + nt*1024

    float4v acc[8][4];
#pragma unroll
    for (int i = 0; i < 8; ++i)
#pragma unroll
        for (int n = 0; n < 4; ++n) acc[i][n] = (float4v){0.f, 0.f, 0.f, 0.f};

#define SLOTB(BF, KH, ISB) (((((BF)*2 + (KH)) * 2) + (ISB)) * 16384)
#define STAGE_A(BF, KH, JJ)                                                  \
    do {                                                                     \
        const ushort_t* s_ = aS + (JJ) * 64 + (KH) * 32;                     \
        char* d_ = LDSc + SLOTB(BF, KH, 0) + wave * 2048;                    \
        gload16(s_, d_);                                                     \
        gload16(s_ + 16 * 1024, d_ + 1024);                                  \
    } while (0)
#define STAGE_B(BF, KH, JJ)                                                  \
    do {                                                                     \
        const ushort_t* s_ = bS + (JJ) * 64 + (KH) * 32;                     \
        char* d_ = LDSc + SLOTB(BF, KH, 1) + wave * 2048;                    \
        gload16(s_, d_);                                                     \
        gload16(s_ + 16 * 1024, d_ + 1024);                                  \
    } while (0)

#define PHASEMFMA(MG)                                                        \
    do {                                                                     \
        __builtin_amdgcn_s_barrier();                                        \
        asm volatile("s_waitcnt lgkmcnt(0)" ::: "memory");                   \
        __builtin_amdgcn_s_setprio(1);                                       \
        _Pragma("unroll") for (int i = 0; i < 4; ++i)                        \
            _Pragma("unroll") for (int nt = 0; nt < 4; ++nt)                 \
                acc[(MG)*4 + i][nt] = __builtin_amdgcn_mfma_f32_16x16x32_bf16( \
                    afr[i], bfr[nt], acc[(MG)*4 + i][nt], 0, 0, 0);          \
        __builtin_amdgcn_s_setprio(0);                                       \
        __builtin_amdgcn_s_barrier();                                        \
    } while (0)

#define KTILE(C, J, VW2, VW4, S12, S34)                                          \
    do {                                                                         \
        short8 bfr[4], afr[4];                                                   \
        /* phase .1: kh0, mg0 */                                                 \
        _Pragma("unroll") for (int nt = 0; nt < 4; ++nt)                         \
            bfr[nt] = *(const short8*)(LDSc + SLOTB(C, 0, 1) + boff + nt * 1024);\
        _Pragma("unroll") for (int i = 0; i < 4; ++i)                            \
            afr[i] = *(const short8*)(LDSc + SLOTB(C, 0, 0) + aoff + i * 1024);  \
        if (S12) STAGE_A(1 - (C), 1, (J) + 1);                                   \
        PHASEMFMA(0);                                                            \
        /* phase .2: kh0, mg1 */                                                 \
        _Pragma("unroll") for (int i = 0; i < 4; ++i)                            \
            afr[i] = *(const short8*)(LDSc + SLOTB(C, 0, 0) + aoff + (4 + i) * 1024); \
        if (S12) STAGE_B(1 - (C), 1, (J) + 1);                                   \
        vm_wait<VW2>();                                                          \
        PHASEMFMA(1);                                                            \
        /* phase .3: kh1, mg0 */                                                 \
        _Pragma("unroll") for (int nt = 0; nt < 4; ++nt)                         \
            bfr[nt] = *(const short8*)(LDSc + SLOTB(C, 1, 1) + boff + nt * 1024);\
        _Pragma("unroll") for (int i = 0; i < 4; ++i)                            \
            afr[i] = *(const short8*)(LDSc + SLOTB(C, 1, 0) + aoff + i * 1024);  \
        if (S34) STAGE_A((C), 0, (J) + 2);                                       \
        PHASEMFMA(0);                                                            \
        /* phase .4: kh1, mg1 */                                                 \
        _Pragma("unroll") for (int i = 0; i < 4; ++i)                            \
            afr[i] = *(const short8*)(LDSc + SLOTB(C, 1, 0) + aoff + (4 + i) * 1024); \
        if (S34) STAGE_B((C), 0, (J) + 2);                                       \
        vm_wait<VW4>();                                                          \
        PHASEMFMA(1);                                                            \
    } while (0)

    // ---- prologue: kh0(0), kh1(0), kh0(1); wait leaves 8 -> kh0(0) landed ----
    STAGE_A(0, 0, 0);
    STAGE_B(0, 0, 0);
    STAGE_A(0, 1, 0);
    STAGE_B(0, 1, 0);
    STAGE_A(1, 0, 1);
    STAGE_B(1, 0, 1);
    vm_wait<8>();
    KBAR();

    // ---- main loop: 16 K-tiles (K=1024) ----
#pragma unroll 1
    for (int j = 0; j < 14; ++j) {
        int c = j & 1;
        KTILE(c, j, 8, 8, 1, 1);
    }
    KTILE(0, 14, 8, 4, 1, 0);
    KTILE(1, 15, 0, -1, 0, 0);

#undef KTILE
#undef PHASEMFMA
#undef STAGE_A
#undef STAGE_B
#undef SLOTB

    // ---- epilogue: wave covers 128 rows x 64 cols = one full head ----
    int nglob = n0 + wn * 64;
    int region = nglob >> 10;          // 0=q, 1=k, 2=v
    int hcol = (nglob & 1023) >> 6;    // head 0..15

    if (region < 2) {
        float scl = (region == 0) ? 0.18033688f : 1.0f;  // 1/8 * log2(e) on Q
        int colbase = region * 1024 + hcol * 64 + l16;
#pragma unroll
        for (int i = 0; i < 8; ++i) {
            int rowb = m0 + wm * 128 + i * 16 + quad * 4;
#pragma unroll
            for (int rr = 0; rr < 4; ++rr) {
                int row = rowb + rr;
                int t = row & 2047;
                const ushort_t* cp = cosb + t * 64 + l16;
                const ushort_t* sp = sinb + t * 64 + l16;
                float c0 = b2f(cp[0]), c1 = b2f(cp[16]), c2 = b2f(cp[32]), c3 = b2f(cp[48]);
                float s0v = b2f(sp[0]), s1v = b2f(sp[16]), s2v = b2f(sp[32]), s3v = b2f(sp[48]);
                float a0 = acc[i][0][rr], a1 = acc[i][1][rr], a2 = acc[i][2][rr], a3 = acc[i][3][rr];
                float o0 = (a0 * c0 - a2 * s0v) * scl;
                float o1 = (a1 * c1 - a3 * s1v) * scl;
                float o2 = (a2 * c2 + a0 * s2v) * scl;
                float o3 = (a3 * c3 + a1 * s3v) * scl;
                size_t base = (size_t)row * 2048 + colbase;
                qk[base] = f2b(o0);
                qk[base + 16] = f2b(o1);
                qk[base + 32] = f2b(o2);
                qk[base + 48] = f2b(o3);
            }
        }
    } else {
        // V: transposed packed store into vt[(b*16+h)*64+d][t]
#pragma unroll
        for (int i = 0; i < 8; ++i) {
            int rowb = m0 + wm * 128 + i * 16 + quad * 4;
            int b = rowb >> 11;
            int t0 = rowb & 2047;
            size_t hb = (size_t)(b * 16 + hcol) * 64;
#pragma unroll
            for (int nt = 0; nt < 4; ++nt) {
                int d = l16 + nt * 16;
                ushort4v pk;
#pragma unroll
                for (int rr = 0; rr < 4; ++rr) pk[rr] = f2b(acc[i][nt][rr]);
                *(ushort4v*)(vt + (hb + d) * 2048 + t0) = pk;
            }
        }
    }
}

// ---------- output projection GEMM: free-drift 256x128 triple-buffer ----------
__global__ __launch_bounds__(512, 2) void gemm_proj(const ushort_t* __restrict__ A, int lda,
                                                    const ushort_t* __restrict__ Bt,
                                                    void* __restrict__ C, int ldc,
                                                    int K,
                                                    const int* __restrict__ flagp) {
    __shared__ ushort_t LDS[73728];  // 144 KB
    char* LDSc = (char*)LDS;

    int tid = threadIdx.x;
    int lane = tid & 63;
    int wave = tid >> 6;
    int wm = wave >> 1;
    int wn = wave & 1;
    int quad = lane >> 4;
    int l16 = lane & 15;

    // grid 256 = 8 xcd * (4 m_loc * 8 n)
    int id = blockIdx.x;
    int xcd = id & 7;
    int r = id >> 3;               // 0..31
    int m0 = (xcd * 4 + (r & 3)) * 256;
    int n0 = (r >> 2) * 128;

    int lrow = lane >> 3;
    int lslot = (lane & 7) ^ lrow;
    const ushort_t* aSrc = A + (size_t)(m0 + wave * 32 + lrow) * lda + lslot * 8;
    const ushort_t* bSrc = Bt + (size_t)(n0 + wave * 16 + lrow) * K + lslot * 8;
    int ldsA_w = (wave * 32) * 128;
    int ldsB_w = (wave * 16) * 128;
    int astr = 8 * lda;
    int bstr = 8 * K;

    int aoff0 = (wm * 64 + l16) * 128 + ((quad ^ (l16 & 7)) * 16);
    int aoff1 = (wm * 64 + l16) * 128 + (((4 + quad) ^ (l16 & 7)) * 16);
    int boff0 = (wn * 64 + l16) * 128 + ((quad ^ (l16 & 7)) * 16);
    int boff1 = (wn * 64 + l16) * 128 + (((4 + quad) ^ (l16 & 7)) * 16);

    float4v acc[4][4];
#pragma unroll
    for (int i = 0; i < 4; ++i)
#pragma unroll
        for (int n = 0; n < 4; ++n) acc[i][n] = (float4v){0.f, 0.f, 0.f, 0.f};

#define STAGE6P(t, jj)                                                      \
    do {                                                                    \
        const ushort_t* as_ = aSrc + (jj) * 64;                             \
        const ushort_t* bs_ = bSrc + (jj) * 64;                             \
        char* al_ = LDSc + (t) * 32768 + ldsA_w;                            \
        char* bl_ = LDSc + 98304 + (t) * 16384 + ldsB_w;                    \
        gload16(as_, al_);                                                  \
        gload16(as_ + astr, al_ + 1024);                                    \
        gload16(as_ + 2 * astr, al_ + 2048);                                \
        gload16(as_ + 3 * astr, al_ + 3072);                                \
        gload16(bs_, bl_);                                                  \
        gload16(bs_ + bstr, bl_ + 1024);                                    \
    } while (0)

#define COMPUTEP(t)                                                         \
    do {                                                                    \
        const char* ab_ = LDSc + (t) * 32768;                               \
        const char* bb_ = LDSc + 98304 + (t) * 16384;                       \
        short8 a0_[4], b0_[4], a1_[4], b1_[4];                              \
        _Pragma("unroll") for (int i = 0; i < 4; ++i) {                     \
            a0_[i] = *(const short8*)(ab_ + aoff0 + i * 2048);              \
            a1_[i] = *(const short8*)(ab_ + aoff1 + i * 2048);              \
        }                                                                   \
        _Pragma("unroll") for (int n = 0; n < 4; ++n) {                     \
            b0_[n] = *(const short8*)(bb_ + boff0 + n * 2048);              \
            b1_[n] = *(const short8*)(bb_ + boff1 + n * 2048);              \
        }                                                                   \
        __builtin_amdgcn_s_setprio(1);                                      \
        _Pragma("unroll") for (int i = 0; i < 4; ++i)                       \
            _Pragma("unroll") for (int n = 0; n < 4; ++n)                   \
                acc[i][n] = __builtin_amdgcn_mfma_f32_16x16x32_bf16(        \
                    a0_[i], b0_[n], acc[i][n], 0, 0, 0);                    \
        _Pragma("unroll") for (int i = 0; i < 4; ++i)                       \
            _Pragma("unroll") for (int n = 0; n < 4; ++n)                   \
                acc[i][n] = __builtin_amdgcn_mfma_f32_16x16x32_bf16(        \
                    a1_[i], b1_[n], acc[i][n], 0, 0, 0);                    \
        __builtin_amdgcn_s_setprio(0);                                      \
    } while (0)

    STAGE6P(0, 0);
    STAGE6P(1, 1);
    vm_wait<6>();
    KBAR();

#pragma unroll 1
    for (int g = 0; g < 4; ++g) {
        int j = g * 3;
        STAGE6P(2, j + 2);
        COMPUTEP(0);
        vm_wait<6>();
        KBAR();
        STAGE6P(0, j + 3);
        COMPUTEP(1);
        vm_wait<6>();
        KBAR();
        STAGE6P(1, j + 4);
        COMPUTEP(2);
        vm_wait<6>();
        KBAR();
    }
    STAGE6P(2, 14);
    COMPUTEP(0);
    vm_wait<6>();
    KBAR();
    STAGE6P(0, 15);
    COMPUTEP(1);
    vm_wait<6>();
    KBAR();
    COMPUTEP(2);
    vm_wait<0>();
    KBAR();
    COMPUTEP(0);

#undef STAGE6P
#undef COMPUTEP

    int f32out = *flagp;
#pragma unroll
    for (int i = 0; i < 4; ++i) {
        int rowb = m0 + wm * 64 + i * 16 + quad * 4;
#pragma unroll
        for (int rr = 0; rr < 4; ++rr) {
            size_t base = (size_t)(rowb + rr) * ldc + n0 + wn * 64 + l16;
            if (f32out) {
                float* Cf = (float*)C;
#pragma unroll
                for (int n = 0; n < 4; ++n) Cf[base + n * 16] = acc[i][n][rr];
            } else {
                ushort_t* Cb = (ushort_t*)C;
#pragma unroll
                for (int n = 0; n < 4; ++n) Cb[base + n * 16] = f2b(acc[i][n][rr]);
            }
        }
    }
}

// ---------- MFMA flash attention: paired q-tiles, bh->XCD pinned ----------
__global__ __launch_bounds__(512, 4) void attn_mfma(ushort_t* qk,
                                                    const ushort_t* __restrict__ vt) {
    __shared__ ushort_t Kl[2][4096];
    __shared__ ushort_t Vl[2][4096];
    __shared__ ushort_t Pl[8 * 16 * 72];

    int tid = threadIdx.x;
    int lane = tid & 63;
    int wave = tid >> 6;
    int quad = lane >> 4;
    int l16 = lane & 15;

    int id = blockIdx.x;
    int bxi = (id >> 3) & 7;
    int bh = (id & 7) * 8 + (id >> 6);
    int b = bh >> 4;
    int h = bh & 15;

    ushort_t* Pw = &Pl[wave * 16 * 72];

    int rr = tid >> 3;
    int sl = (tid & 7) ^ (rr & 7);
    const ushort_t* ksrc = qk + (size_t)(b * 2048 + rr) * 2048 + 1024 + h * 64 + sl * 8;
    const ushort_t* vsrc = vt + (size_t)(bh * 64 + rr) * 2048 + sl * 8;
    char* kdst = (char*)&Kl[0][0] + wave * 1024;
    char* vdst = (char*)&Vl[0][0] + wave * 1024;

    int swr = l16 & 7;

#pragma unroll 1
    for (int phase = 0; phase < 2; ++phase) {
        int qt = phase ? bxi : (15 - bxi);
        int row0 = qt * 128 + wave * 16;
        size_t qbase = ((size_t)(b * 2048 + row0)) * 2048 + h * 64;

        short8 qf[2];
        {
            const ushort_t* p = qk + qbase + (size_t)l16 * 2048 + quad * 8;
            qf[0] = *(const short8*)p;
            qf[1] = *(const short8*)(p + 32);
        }

        float4v oacc[4];
#pragma unroll
        for (int nt = 0; nt < 4; ++nt) oacc[nt] = (float4v){0.f, 0.f, 0.f, 0.f};
        float psum[4];
#pragma unroll
        for (int r = 0; r < 4; ++r) psum[r] = 0.f;

        int ntiles = 2 * qt + 2;

        gload16(ksrc, kdst);
        gload16(vsrc, vdst);
        vm_wait<0>();
        KBAR();

        for (int st = 0; st < ntiles; ++st) {
            int s0 = st * 64;
            int buf = st & 1;

            if (st + 1 < ntiles) {
                gload16(ksrc + (size_t)(s0 + 64) * 2048, kdst + ((st + 1) & 1) * 8192);
                gload16(vsrc + (s0 + 64), vdst + ((st + 1) & 1) * 8192);
            }

            if (s0 <= row0 + 15) {
                const char* kb = (const char*)&Kl[buf][0];
                const char* vb = (const char*)&Vl[buf][0];

                float4v sacc[4];
#pragma unroll
                for (int ct = 0; ct < 4; ++ct) sacc[ct] = (float4v){0.f, 0.f, 0.f, 0.f};
#pragma unroll
                for (int ks = 0; ks < 2; ++ks) {
                    short8 bfr[4];
#pragma unroll
                    for (int ct = 0; ct < 4; ++ct)
                        bfr[ct] = *(const short8*)(kb + (ct * 16 + l16) * 128 +
                                                   (((ks * 4 + quad) ^ swr) * 16));
                    __builtin_amdgcn_s_setprio(1);
#pragma unroll
                    for (int ct = 0; ct < 4; ++ct)
                        sacc[ct] = __builtin_amdgcn_mfma_f32_16x16x32_bf16(
                            qf[ks], bfr[ct], sacc[ct], 0, 0, 0);
                    __builtin_amdgcn_s_setprio(0);
                }

                if ((s0 + 63) > row0) {
#pragma unroll
                    for (int r = 0; r < 4; ++r) {
                        int trow = row0 + quad * 4 + r;
                        float ps = 0.f;
#pragma unroll
                        for (int ct = 0; ct < 4; ++ct) {
                            float p = exp2f(sacc[ct][r]);
                            if ((s0 + ct * 16 + l16) > trow) p = 0.f;
                            ps += p;
                            Pw[(quad * 4 + r) * 72 + ct * 16 + l16] = f2b_trunc(p);
                        }
                        psum[r] += ps;
                    }
                } else {
#pragma unroll
                    for (int r = 0; r < 4; ++r) {
                        float ps = 0.f;
#pragma unroll
                        for (int ct = 0; ct < 4; ++ct) {
                            float p = exp2f(sacc[ct][r]);
                            ps += p;
                            Pw[(quad * 4 + r) * 72 + ct * 16 + l16] = f2b_trunc(p);
                        }
                        psum[r] += ps;
                    }
                }

#pragma unroll
                for (int ks = 0; ks < 2; ++ks) {
                    short8 bfr[4];
#pragma unroll
                    for (int nt = 0; nt < 4; ++nt)
                        bfr[nt] = *(const short8*)(vb + (nt * 16 + l16) * 128 +
                                                   (((ks * 4 + quad) ^ swr) * 16));
                    short8 af = *(const short8*)(&Pw[l16 * 72 + ks * 32 + quad * 8]);
                    __builtin_amdgcn_s_setprio(1);
#pragma unroll
                    for (int nt = 0; nt < 4; ++nt)
                        oacc[nt] = __builtin_amdgcn_mfma_f32_16x16x32_bf16(
                            af, bfr[nt], oacc[nt], 0, 0, 0);
                    __builtin_amdgcn_s_setprio(0);
                }
            }

            vm_wait<0>();
            KBAR();
        }

#pragma unroll
        for (int r = 0; r < 4; ++r) {
            float ps = psum[r];
#pragma unroll
            for (int off = 1; off < 16; off <<= 1) ps += __shfl_xor(ps, off);
            float inv = 1.0f / ps;
            size_t base = qbase + (size_t)(quad * 4 + r) * 2048;
#pragma unroll
            for (int nt = 0; nt < 4; ++nt)
                qk[base + nt * 16 + l16] = f2b(oacc[nt][r] * inv);
        }
    }
}

// ---------- launch ----------
extern "C" void kernel_launch(void* const* d_in, const int* in_sizes, int n_in,
                              void* d_out, int out_size, void* d_ws, size_t ws_size,
                              hipStream_t stream) {
    const void* x = d_in[0];
    const void* cosp = d_in[1];
    const void* sinp = d_in[2];
    const void* Wq = d_in[3];
    const void* Wk = d_in[4];
    const void* Wv = d_in[5];
    const void* Wo = d_in[6];

    char* ws = (char*)d_ws;
    int* flag = (int*)ws;
    ushort_t* vtg = (ushort_t*)(ws + 256);                        // 16.8 MB
    ushort_t* qk = vtg + (size_t)8192 * 2048;                     // 33.6 MB
    ushort_t* WT = qk + (size_t)8192 * 2048;                      // 4 x 2 MB (Wq|Wk|Wv|Wo)^T
    ushort_t* WoT = WT + (size_t)3 * 1024 * 1024;
    ushort_t* cosb = WT + (size_t)4 * 1024 * 1024;
    ushort_t* sinb = cosb + (size_t)2048 * 64;
    ushort_t* xb = sinb + (size_t)2048 * 64;                      // 16.8 MB (fp32 mode only)

    detect_dtype<<<1, 64, 0, stream>>>((const ushort_t*)cosp, flag);
    prep_all<<<dim3(32, 32, 13), 256, 0, stream>>>(x, xb, cosp, sinp, cosb, sinb,
                                                   Wq, Wk, Wv, Wo, WT, flag);

    gemm_qkv<<<384, 512, 0, stream>>>((const ushort_t*)x, xb, WT, qk, vtg, cosb, sinb, flag);

    attn_mfma<<<512, 512, 0, stream>>>(qk, vtg);

    gemm_proj<<<256, 512, 0, stream>>>(qk, 2048, WoT, d_out, 1024, 1024, flag);
}

// Round 11
// 240.007 us; speedup vs baseline: 1.0927x; 1.0927x over previous
//
#include <hip/hip_runtime.h>
#include <cstdint>
#include <cstddef>

typedef unsigned short ushort_t;
typedef __attribute__((ext_vector_type(8))) short short8;
typedef __attribute__((ext_vector_type(4))) float float4v;
typedef __attribute__((ext_vector_type(4))) unsigned short ushort4v;

// ---------- bf16 helpers ----------
__device__ __forceinline__ float b2f(ushort_t u) {
    uint32_t x = ((uint32_t)u) << 16;
    float f;
    __builtin_memcpy(&f, &x, 4);
    return f;
}
__device__ __forceinline__ ushort_t f2b(float f) {  // RNE
    uint32_t x;
    __builtin_memcpy(&x, &f, 4);
    uint32_t r = (x + 0x7fffu + ((x >> 16) & 1u)) >> 16;
    return (ushort_t)r;
}
__device__ __forceinline__ ushort_t f2b_trunc(float f) {  // truncate (P-matrix only)
    uint32_t x;
    __builtin_memcpy(&x, &f, 4);
    return (ushort_t)(x >> 16);
}

// ---------- direct global->LDS (16B/lane; LDS dest = wave-uniform base + lane*16) ----------
typedef __attribute__((address_space(3))) void lds_void;
typedef __attribute__((address_space(1))) const void gbl_void;
__device__ __forceinline__ void gload16(const void* g, void* l) {
    __builtin_amdgcn_global_load_lds((gbl_void*)(uintptr_t)g, (lds_void*)(uintptr_t)l, 16, 0, 0);
}

// ---------- dtype detector ----------
__global__ void detect_dtype(const ushort_t* __restrict__ cosp, int* __restrict__ flag) {
    int tid = threadIdx.x;
    int bad = 0;
    for (int i = tid; i < 512; i += 64) {
        ushort_t u = cosp[i];
        int sign = u >> 15;
        int e = (u >> 7) & 0xFF;
        if (sign || e > 126) bad = 1;
    }
    int anybad = __any(bad);
    if (tid == 0) *flag = anybad ? 1 : 0;  // 1 => inputs are fp32
}

// ---------- merged preprocessing: W-transpose (z 0-3), cos/sin (z 4), X convert (z 5-12) ----------
__global__ __launch_bounds__(256) void prep_all(const void* __restrict__ x,
                                                ushort_t* __restrict__ xb,
                                                const void* __restrict__ c,
                                                const void* __restrict__ s,
                                                ushort_t* __restrict__ cb,
                                                ushort_t* __restrict__ sb,
                                                const void* __restrict__ w0,
                                                const void* __restrict__ w1,
                                                const void* __restrict__ w2,
                                                const void* __restrict__ w3,
                                                ushort_t* __restrict__ wt,
                                                const int* __restrict__ flag) {
    __shared__ ushort_t tile[32][33];
    int z = blockIdx.z;
    int f = *flag;
    if (z < 4) {
        // transpose weight z -> wt + z*1M
        const void* in = (z == 0) ? w0 : (z == 1) ? w1 : (z == 2) ? w2 : w3;
        ushort_t* o = wt + (size_t)z * 1024 * 1024;
        int bx = blockIdx.x * 32;
        int by = blockIdx.y * 32;
        int tx = threadIdx.x & 31;
        int ty = threadIdx.x >> 5;
        for (int r = ty; r < 32; r += 8) {
            size_t idx = (size_t)(by + r) * 1024 + bx + tx;
            tile[r][tx] = f ? f2b(((const float*)in)[idx]) : ((const ushort_t*)in)[idx];
        }
        __syncthreads();
        for (int r = ty; r < 32; r += 8)
            o[(size_t)(bx + r) * 1024 + by + tx] = tile[tx][r];
    } else if (z == 4) {
        // cos/sin -> canonical bf16 (131072 elems)
        int i = (blockIdx.y * 32 + blockIdx.x) * 256 + threadIdx.x;
        if (i < 131072) {
            if (f) {
                cb[i] = f2b(((const float*)c)[i]);
                sb[i] = f2b(((const float*)s)[i]);
            } else {
                cb[i] = ((const ushort_t*)c)[i];
                sb[i] = ((const ushort_t*)s)[i];
            }
        }
    } else {
        // X fp32 -> bf16 (fp32 mode only); slice z-5 of 8
        if (f == 0) return;
        int bid = (z - 5) * 1024 + blockIdx.y * 32 + blockIdx.x;
        int i = (bid * 256 + threadIdx.x) * 4;
        float4v v = *(const float4v*)((const float*)x + i);
        ushort4v o4;
#pragma unroll
        for (int j = 0; j < 4; ++j) o4[j] = f2b(v[j]);
        *(ushort4v*)(xb + i) = o4;
    }
}

// ====================================================================
// fused QKV GEMM + RoPE + V-transpose — 256x128 tile, BK=64,
// TRIPLE-buffered free-drift schedule (one barrier + one vmcnt(6)/tile).
// XCD pinning on the X (A) axis (FETCH 204->51 MB verified r8).
// Q region is pre-scaled by 0.125*log2(e) so attn softmax = exp2(raw).
// NOTE: two m201-style 8-phase ports (r2, r10) both LOST to this
// structure (102 us and 83 us vs 77): phase-lockstep + imperfect swizzle
// + 1 block/CU occupancy. Keep free-drift.
// ====================================================================
template <int W>
__device__ __forceinline__ void vm_wait() {
    if constexpr (W == 6)      asm volatile("s_waitcnt vmcnt(6)" ::: "memory");
    else                       asm volatile("s_waitcnt vmcnt(0)" ::: "memory");
}
#define KBAR()                                       \
    do {                                             \
        asm volatile("" ::: "memory");               \
        __builtin_amdgcn_s_barrier();                \
        asm volatile("" ::: "memory");               \
    } while (0)

__global__ __launch_bounds__(512, 2) void gemm_qkv(const ushort_t* __restrict__ X0,
                                                   const ushort_t* __restrict__ X1,
                                                   const ushort_t* __restrict__ Wt,
                                                   ushort_t* __restrict__ qk,
                                                   ushort_t* __restrict__ vt,
                                                   const ushort_t* __restrict__ cosb,
                                                   const ushort_t* __restrict__ sinb,
                                                   const int* __restrict__ flagp) {
    __shared__ ushort_t LDS[73728];  // 144 KB
    char* LDSc = (char*)LDS;

    int tid = threadIdx.x;
    int lane = tid & 63;
    int wave = tid >> 6;   // 0..7
    int wm = wave >> 1;    // 0..3  (M quarter: 64 rows)
    int wn = wave & 1;     // 0..1  (N half: 64 cols)
    int quad = lane >> 4;
    int l16 = lane & 15;

    // grid 768 = 8 xcd * (4 m_loc * 24 n): X slice (4 panels, 2MB) pinned per XCD.
    int id = blockIdx.x;
    int xcd = id & 7;
    int r = id >> 3;               // 0..95
    int m0 = (xcd * 4 + (r & 3)) * 256;
    int n0 = (r >> 2) * 128;

    const ushort_t* Xb = (*flagp) ? X1 : X0;

    // staging source (pre-swizzled): lane l covers dest row +l>>3, slot l&7
    int lrow = lane >> 3;            // 0..7
    int lslot = (lane & 7) ^ lrow;   // inverse swizzle on source k-slot
    const ushort_t* aSrc = Xb + (size_t)(m0 + wave * 32 + lrow) * 1024 + lslot * 8;
    const ushort_t* bSrc = Wt + (size_t)(n0 + wave * 16 + lrow) * 1024 + lslot * 8;
    int ldsA_w = (wave * 32) * 128;
    int ldsB_w = (wave * 16) * 128;

    // frag read offsets (bytes within buf); slot swizzle s' = s ^ (l16&7)
    int aoff0 = (wm * 64 + l16) * 128 + ((quad ^ (l16 & 7)) * 16);
    int aoff1 = (wm * 64 + l16) * 128 + (((4 + quad) ^ (l16 & 7)) * 16);
    int boff0 = (wn * 64 + l16) * 128 + ((quad ^ (l16 & 7)) * 16);
    int boff1 = (wn * 64 + l16) * 128 + (((4 + quad) ^ (l16 & 7)) * 16);

    float4v acc[4][4];
#pragma unroll
    for (int i = 0; i < 4; ++i)
#pragma unroll
        for (int n = 0; n < 4; ++n) acc[i][n] = (float4v){0.f, 0.f, 0.f, 0.f};

#define STAGE6(t, jj)                                                       \
    do {                                                                    \
        const ushort_t* as_ = aSrc + (jj) * 64;                             \
        const ushort_t* bs_ = bSrc + (jj) * 64;                             \
        char* al_ = LDSc + (t) * 32768 + ldsA_w;                            \
        char* bl_ = LDSc + 98304 + (t) * 16384 + ldsB_w;                    \
        gload16(as_, al_);                                                  \
        gload16(as_ + 8 * 1024, al_ + 1024);                                \
        gload16(as_ + 16 * 1024, al_ + 2048);                               \
        gload16(as_ + 24 * 1024, al_ + 3072);                               \
        gload16(bs_, bl_);                                                  \
        gload16(bs_ + 8 * 1024, bl_ + 1024);                                \
    } while (0)

#define COMPUTE(t)                                                          \
    do {                                                                    \
        const char* ab_ = LDSc + (t) * 32768;                               \
        const char* bb_ = LDSc + 98304 + (t) * 16384;                       \
        short8 a0_[4], b0_[4], a1_[4], b1_[4];                              \
        _Pragma("unroll") for (int i = 0; i < 4; ++i) {                     \
            a0_[i] = *(const short8*)(ab_ + aoff0 + i * 2048);              \
            a1_[i] = *(const short8*)(ab_ + aoff1 + i * 2048);              \
        }                                                                   \
        _Pragma("unroll") for (int n = 0; n < 4; ++n) {                     \
            b0_[n] = *(const short8*)(bb_ + boff0 + n * 2048);              \
            b1_[n] = *(const short8*)(bb_ + boff1 + n * 2048);              \
        }                                                                   \
        __builtin_amdgcn_s_setprio(1);                                      \
        _Pragma("unroll") for (int i = 0; i < 4; ++i)                       \
            _Pragma("unroll") for (int n = 0; n < 4; ++n)                   \
                acc[i][n] = __builtin_amdgcn_mfma_f32_16x16x32_bf16(        \
                    a0_[i], b0_[n], acc[i][n], 0, 0, 0);                    \
        _Pragma("unroll") for (int i = 0; i < 4; ++i)                       \
            _Pragma("unroll") for (int n = 0; n < 4; ++n)                   \
                acc[i][n] = __builtin_amdgcn_mfma_f32_16x16x32_bf16(        \
                    a1_[i], b1_[n], acc[i][n], 0, 0, 0);                    \
        __builtin_amdgcn_s_setprio(0);                                      \
    } while (0)

    STAGE6(0, 0);
    STAGE6(1, 1);
    vm_wait<6>();
    KBAR();

#pragma unroll 1
    for (int g = 0; g < 4; ++g) {
        int j = g * 3;
        STAGE6(2, j + 2);
        COMPUTE(0);
        vm_wait<6>();
        KBAR();
        STAGE6(0, j + 3);
        COMPUTE(1);
        vm_wait<6>();
        KBAR();
        STAGE6(1, j + 4);
        COMPUTE(2);
        vm_wait<6>();
        KBAR();
    }
    STAGE6(2, 14);
    COMPUTE(0);
    vm_wait<6>();
    KBAR();
    STAGE6(0, 15);
    COMPUTE(1);
    vm_wait<6>();
    KBAR();
    COMPUTE(2);
    vm_wait<0>();
    KBAR();
    COMPUTE(0);

#undef STAGE6
#undef COMPUTE

    // epilogue: wave covers 64 rows x 64 cols = one head of one region
    int nglob = n0 + wn * 64;
    int region = nglob >> 10;          // 0=q, 1=k, 2=v
    int hcol = (nglob & 1023) >> 6;    // head 0..15

    if (region < 2) {
        float scl = (region == 0) ? 0.18033688f : 1.0f;  // 1/8 * log2(e) on Q
        int colbase = region * 1024 + hcol * 64 + l16;
#pragma unroll
        for (int i = 0; i < 4; ++i) {
            int rowb = m0 + wm * 64 + i * 16 + quad * 4;
#pragma unroll
            for (int rr = 0; rr < 4; ++rr) {
                int row = rowb + rr;
                int t = row & 2047;
                const ushort_t* cp = cosb + t * 64 + l16;
                const ushort_t* sp = sinb + t * 64 + l16;
                float c0 = b2f(cp[0]), c1 = b2f(cp[16]), c2 = b2f(cp[32]), c3 = b2f(cp[48]);
                float s0v = b2f(sp[0]), s1v = b2f(sp[16]), s2v = b2f(sp[32]), s3v = b2f(sp[48]);
                float a0 = acc[i][0][rr], a1 = acc[i][1][rr], a2 = acc[i][2][rr], a3 = acc[i][3][rr];
                float o0 = (a0 * c0 - a2 * s0v) * scl;
                float o1 = (a1 * c1 - a3 * s1v) * scl;
                float o2 = (a2 * c2 + a0 * s2v) * scl;
                float o3 = (a3 * c3 + a1 * s3v) * scl;
                size_t base = (size_t)row * 2048 + colbase;
                qk[base] = f2b(o0);
                qk[base + 16] = f2b(o1);
                qk[base + 32] = f2b(o2);
                qk[base + 48] = f2b(o3);
            }
        }
    } else {
        // V: transposed packed store into vt[(b*16+h)*64+d][t]
#pragma unroll
        for (int i = 0; i < 4; ++i) {
            int rowb = m0 + wm * 64 + i * 16 + quad * 4;
            int b = rowb >> 11;
            int t0 = rowb & 2047;
            size_t hb = (size_t)(b * 16 + hcol) * 64;
#pragma unroll
            for (int n = 0; n < 4; ++n) {
                int d = l16 + n * 16;
                ushort4v pk;
#pragma unroll
                for (int rr = 0; rr < 4; ++rr) pk[rr] = f2b(acc[i][n][rr]);
                *(ushort4v*)(vt + (hb + d) * 2048 + t0) = pk;
            }
        }
    }
}

// ---------- output projection GEMM: free-drift 256x128 triple-buffer ----------
// Same K-loop as gemm_qkv (lda/K parameterized). Grid 256 = 8 xcd x 32 =
// exactly ONE residency round (1 block/CU), A(m)-slice pinned per XCD.
__global__ __launch_bounds__(512, 2) void gemm_proj(const ushort_t* __restrict__ A, int lda,
                                                    const ushort_t* __restrict__ Bt,
                                                    void* __restrict__ C, int ldc,
                                                    int K,
                                                    const int* __restrict__ flagp) {
    __shared__ ushort_t LDS[73728];  // 144 KB
    char* LDSc = (char*)LDS;

    int tid = threadIdx.x;
    int lane = tid & 63;
    int wave = tid >> 6;
    int wm = wave >> 1;
    int wn = wave & 1;
    int quad = lane >> 4;
    int l16 = lane & 15;

    // grid 256 = 8 xcd * (4 m_loc * 8 n)
    int id = blockIdx.x;
    int xcd = id & 7;
    int r = id >> 3;               // 0..31
    int m0 = (xcd * 4 + (r & 3)) * 256;
    int n0 = (r >> 2) * 128;

    int lrow = lane >> 3;
    int lslot = (lane & 7) ^ lrow;
    const ushort_t* aSrc = A + (size_t)(m0 + wave * 32 + lrow) * lda + lslot * 8;
    const ushort_t* bSrc = Bt + (size_t)(n0 + wave * 16 + lrow) * K + lslot * 8;
    int ldsA_w = (wave * 32) * 128;
    int ldsB_w = (wave * 16) * 128;
    int astr = 8 * lda;   // 8-row stride in elements
    int bstr = 8 * K;

    int aoff0 = (wm * 64 + l16) * 128 + ((quad ^ (l16 & 7)) * 16);
    int aoff1 = (wm * 64 + l16) * 128 + (((4 + quad) ^ (l16 & 7)) * 16);
    int boff0 = (wn * 64 + l16) * 128 + ((quad ^ (l16 & 7)) * 16);
    int boff1 = (wn * 64 + l16) * 128 + (((4 + quad) ^ (l16 & 7)) * 16);

    float4v acc[4][4];
#pragma unroll
    for (int i = 0; i < 4; ++i)
#pragma unroll
        for (int n = 0; n < 4; ++n) acc[i][n] = (float4v){0.f, 0.f, 0.f, 0.f};

#define STAGE6P(t, jj)                                                      \
    do {                                                                    \
        const ushort_t* as_ = aSrc + (jj) * 64;                             \
        const ushort_t* bs_ = bSrc + (jj) * 64;                             \
        char* al_ = LDSc + (t) * 32768 + ldsA_w;                            \
        char* bl_ = LDSc + 98304 + (t) * 16384 + ldsB_w;                    \
        gload16(as_, al_);                                                  \
        gload16(as_ + astr, al_ + 1024);                                    \
        gload16(as_ + 2 * astr, al_ + 2048);                                \
        gload16(as_ + 3 * astr, al_ + 3072);                                \
        gload16(bs_, bl_);                                                  \
        gload16(bs_ + bstr, bl_ + 1024);                                    \
    } while (0)

#define COMPUTEP(t)                                                         \
    do {                                                                    \
        const char* ab_ = LDSc + (t) * 32768;                               \
        const char* bb_ = LDSc + 98304 + (t) * 16384;                       \
        short8 a0_[4], b0_[4], a1_[4], b1_[4];                              \
        _Pragma("unroll") for (int i = 0; i < 4; ++i) {                     \
            a0_[i] = *(const short8*)(ab_ + aoff0 + i * 2048);              \
            a1_[i] = *(const short8*)(ab_ + aoff1 + i * 2048);              \
        }                                                                   \
        _Pragma("unroll") for (int n = 0; n < 4; ++n) {                     \
            b0_[n] = *(const short8*)(bb_ + boff0 + n * 2048);              \
            b1_[n] = *(const short8*)(bb_ + boff1 + n * 2048);              \
        }                                                                   \
        __builtin_amdgcn_s_setprio(1);                                      \
        _Pragma("unroll") for (int i = 0; i < 4; ++i)                       \
            _Pragma("unroll") for (int n = 0; n < 4; ++n)                   \
                acc[i][n] = __builtin_amdgcn_mfma_f32_16x16x32_bf16(        \
                    a0_[i], b0_[n], acc[i][n], 0, 0, 0);                    \
        _Pragma("unroll") for (int i = 0; i < 4; ++i)                       \
            _Pragma("unroll") for (int n = 0; n < 4; ++n)                   \
                acc[i][n] = __builtin_amdgcn_mfma_f32_16x16x32_bf16(        \
                    a1_[i], b1_[n], acc[i][n], 0, 0, 0);                    \
        __builtin_amdgcn_s_setprio(0);                                      \
    } while (0)

    STAGE6P(0, 0);
    STAGE6P(1, 1);
    vm_wait<6>();
    KBAR();

#pragma unroll 1
    for (int g = 0; g < 4; ++g) {
        int j = g * 3;
        STAGE6P(2, j + 2);
        COMPUTEP(0);
        vm_wait<6>();
        KBAR();
        STAGE6P(0, j + 3);
        COMPUTEP(1);
        vm_wait<6>();
        KBAR();
        STAGE6P(1, j + 4);
        COMPUTEP(2);
        vm_wait<6>();
        KBAR();
    }
    STAGE6P(2, 14);
    COMPUTEP(0);
    vm_wait<6>();
    KBAR();
    STAGE6P(0, 15);
    COMPUTEP(1);
    vm_wait<6>();
    KBAR();
    COMPUTEP(2);
    vm_wait<0>();
    KBAR();
    COMPUTEP(0);

#undef STAGE6P
#undef COMPUTEP

    int f32out = *flagp;
#pragma unroll
    for (int i = 0; i < 4; ++i) {
        int rowb = m0 + wm * 64 + i * 16 + quad * 4;
#pragma unroll
        for (int rr = 0; rr < 4; ++rr) {
            size_t base = (size_t)(rowb + rr) * ldc + n0 + wn * 64 + l16;
            if (f32out) {
                float* Cf = (float*)C;
#pragma unroll
                for (int n = 0; n < 4; ++n) Cf[base + n * 16] = acc[i][n][rr];
            } else {
                ushort_t* Cb = (ushort_t*)C;
#pragma unroll
                for (int n = 0; n < 4; ++n) Cb[base + n * 16] = f2b(acc[i][n][rr]);
            }
        }
    }
}

// ---------- MFMA flash attention: paired q-tiles (uniform 34 tiles/block), ----------
// 8 waves x 16 rows, double-buffered K/V via global_load_lds (1 barrier/tile),
// XOR-swizzled LDS, Q pre-scaled so softmax = exp2(raw), setprio on MFMA.
// bh->XCD pinning (FETCH 147->29.6 MB verified r9): id = (bh_hi:3|bxi:3|grp:3);
// all 64 blocks of one group share one XCD; K/V hot set 4 MB = its L2.
// NOTE: (512,8) forced 32 VGPR + scratch spills -- never. Single-qt split
// (imbalanced, all co-resident) ran 136 us vs paired 84 -- keep pairing.
__global__ __launch_bounds__(512, 4) void attn_mfma(ushort_t* qk,
                                                    const ushort_t* __restrict__ vt) {
    __shared__ ushort_t Kl[2][4096];   // [buf][64 rows x 64 cols], swizzled
    __shared__ ushort_t Vl[2][4096];
    __shared__ ushort_t Pl[8 * 16 * 72];

    int tid = threadIdx.x;
    int lane = tid & 63;
    int wave = tid >> 6;   // 0..7
    int quad = lane >> 4;
    int l16 = lane & 15;

    int id = blockIdx.x;
    int bxi = (id >> 3) & 7;             // 0..7 (q-tile pair index)
    int bh = (id & 7) * 8 + (id >> 6);   // bh group pinned to XCD id&7
    int b = bh >> 4;
    int h = bh & 15;

    ushort_t* Pw = &Pl[wave * 16 * 72];

    int rr = tid >> 3;                 // 0..63
    int sl = (tid & 7) ^ (rr & 7);     // pre-swizzled source slot
    const ushort_t* ksrc = qk + (size_t)(b * 2048 + rr) * 2048 + 1024 + h * 64 + sl * 8;
    const ushort_t* vsrc = vt + (size_t)(bh * 64 + rr) * 2048 + sl * 8;
    char* kdst = (char*)&Kl[0][0] + wave * 1024;
    char* vdst = (char*)&Vl[0][0] + wave * 1024;

    int swr = l16 & 7;  // row-swizzle key for frag reads

#pragma unroll 1
    for (int phase = 0; phase < 2; ++phase) {
        int qt = phase ? bxi : (15 - bxi);
        int row0 = qt * 128 + wave * 16;
        size_t qbase = ((size_t)(b * 2048 + row0)) * 2048 + h * 64;

        short8 qf[2];
        {
            const ushort_t* p = qk + qbase + (size_t)l16 * 2048 + quad * 8;
            qf[0] = *(const short8*)p;
            qf[1] = *(const short8*)(p + 32);
        }

        float4v oacc[4];
#pragma unroll
        for (int nt = 0; nt < 4; ++nt) oacc[nt] = (float4v){0.f, 0.f, 0.f, 0.f};
        float psum[4];
#pragma unroll
        for (int r = 0; r < 4; ++r) psum[r] = 0.f;

        int ntiles = 2 * qt + 2;

        gload16(ksrc, kdst);
        gload16(vsrc, vdst);
        vm_wait<0>();
        KBAR();

        for (int st = 0; st < ntiles; ++st) {
            int s0 = st * 64;
            int buf = st & 1;

            if (st + 1 < ntiles) {
                gload16(ksrc + (size_t)(s0 + 64) * 2048, kdst + ((st + 1) & 1) * 8192);
                gload16(vsrc + (s0 + 64), vdst + ((st + 1) & 1) * 8192);
            }

            if (s0 <= row0 + 15) {
                const char* kb = (const char*)&Kl[buf][0];
                const char* vb = (const char*)&Vl[buf][0];

                // ---- QK^T ----
                float4v sacc[4];
#pragma unroll
                for (int ct = 0; ct < 4; ++ct) sacc[ct] = (float4v){0.f, 0.f, 0.f, 0.f};
#pragma unroll
                for (int ks = 0; ks < 2; ++ks) {
                    short8 bfr[4];
#pragma unroll
                    for (int ct = 0; ct < 4; ++ct)
                        bfr[ct] = *(const short8*)(kb + (ct * 16 + l16) * 128 +
                                                   (((ks * 4 + quad) ^ swr) * 16));
                    __builtin_amdgcn_s_setprio(1);
#pragma unroll
                    for (int ct = 0; ct < 4; ++ct)
                        sacc[ct] = __builtin_amdgcn_mfma_f32_16x16x32_bf16(
                            qf[ks], bfr[ct], sacc[ct], 0, 0, 0);
                    __builtin_amdgcn_s_setprio(0);
                }

                // ---- softmax (Q pre-scaled: p = exp2(score)) ----
                if ((s0 + 63) > row0) {   // diagonal tile: per-element mask
#pragma unroll
                    for (int r = 0; r < 4; ++r) {
                        int trow = row0 + quad * 4 + r;
                        float ps = 0.f;
#pragma unroll
                        for (int ct = 0; ct < 4; ++ct) {
                            float p = exp2f(sacc[ct][r]);
                            if ((s0 + ct * 16 + l16) > trow) p = 0.f;
                            ps += p;
                            Pw[(quad * 4 + r) * 72 + ct * 16 + l16] = f2b_trunc(p);
                        }
                        psum[r] += ps;
                    }
                } else {                  // full tile: no compares
#pragma unroll
                    for (int r = 0; r < 4; ++r) {
                        float ps = 0.f;
#pragma unroll
                        for (int ct = 0; ct < 4; ++ct) {
                            float p = exp2f(sacc[ct][r]);
                            ps += p;
                            Pw[(quad * 4 + r) * 72 + ct * 16 + l16] = f2b_trunc(p);
                        }
                        psum[r] += ps;
                    }
                }

                // ---- PV ----
#pragma unroll
                for (int ks = 0; ks < 2; ++ks) {
                    short8 bfr[4];
#pragma unroll
                    for (int nt = 0; nt < 4; ++nt)
                        bfr[nt] = *(const short8*)(vb + (nt * 16 + l16) * 128 +
                                                   (((ks * 4 + quad) ^ swr) * 16));
                    short8 af = *(const short8*)(&Pw[l16 * 72 + ks * 32 + quad * 8]);
                    __builtin_amdgcn_s_setprio(1);
#pragma unroll
                    for (int nt = 0; nt < 4; ++nt)
                        oacc[nt] = __builtin_amdgcn_mfma_f32_16x16x32_bf16(
                            af, bfr[nt], oacc[nt], 0, 0, 0);
                    __builtin_amdgcn_s_setprio(0);
                }
            }

            vm_wait<0>();
            KBAR();
        }

        // ---- epilogue: normalize and store ----
#pragma unroll
        for (int r = 0; r < 4; ++r) {
            float ps = psum[r];
#pragma unroll
            for (int off = 1; off < 16; off <<= 1) ps += __shfl_xor(ps, off);
            float inv = 1.0f / ps;
            size_t base = qbase + (size_t)(quad * 4 + r) * 2048;
#pragma unroll
            for (int nt = 0; nt < 4; ++nt)
                qk[base + nt * 16 + l16] = f2b(oacc[nt][r] * inv);
        }
    }
}

// ---------- launch ----------
extern "C" void kernel_launch(void* const* d_in, const int* in_sizes, int n_in,
                              void* d_out, int out_size, void* d_ws, size_t ws_size,
                              hipStream_t stream) {
    const void* x = d_in[0];
    const void* cosp = d_in[1];
    const void* sinp = d_in[2];
    const void* Wq = d_in[3];
    const void* Wk = d_in[4];
    const void* Wv = d_in[5];
    const void* Wo = d_in[6];

    char* ws = (char*)d_ws;
    int* flag = (int*)ws;
    ushort_t* vtg = (ushort_t*)(ws + 256);                        // 16.8 MB
    ushort_t* qk = vtg + (size_t)8192 * 2048;                     // 33.6 MB
    ushort_t* WT = qk + (size_t)8192 * 2048;                      // 4 x 2 MB (Wq|Wk|Wv|Wo)^T
    ushort_t* WoT = WT + (size_t)3 * 1024 * 1024;
    ushort_t* cosb = WT + (size_t)4 * 1024 * 1024;
    ushort_t* sinb = cosb + (size_t)2048 * 64;
    ushort_t* xb = sinb + (size_t)2048 * 64;                      // 16.8 MB (fp32 mode only)

    detect_dtype<<<1, 64, 0, stream>>>((const ushort_t*)cosp, flag);
    prep_all<<<dim3(32, 32, 13), 256, 0, stream>>>(x, xb, cosp, sinp, cosb, sinb,
                                                   Wq, Wk, Wv, Wo, WT, flag);

    gemm_qkv<<<768, 512, 0, stream>>>((const ushort_t*)x, xb, WT, qk, vtg, cosb, sinb, flag);

    attn_mfma<<<512, 512, 0, stream>>>(qk, vtg);

    gemm_proj<<<256, 512, 0, stream>>>(qk, 2048, WoT, d_out, 1024, 1024, flag);
}